// Round 1
// baseline (2374.782 us; speedup 1.0000x reference)
//
#include <hip/hip_runtime.h>
#include <stdint.h>

#define BB 16
#define CC 4
#define HH 512
#define WW 512
#define NWORDS 8          // 512 / 64
#define HW (HH * WW)

// ---------------- ws layout ----------------
// [0]                 : double acc
// [64 .. 64+512)      : unsigned flags[128]  (0..63 tgt_present[c*16+b], 64..127 pred_nonzero)
// [4096 .. +2MB)      : u64 tgt_bits [C][B][H][NWORDS]
// [+2MB .. +4MB)      : u64 ppos_bits[C][B][H][NWORDS]  (p==1.0)
// [+4MB .. +6MB)      : u64 pneg_bits[C][B][H][NWORDS]  (p==0.0)
#define OFF_FLAGS 64
#define OFF_TGT   4096
#define BOARD_BYTES (CC * BB * HH * NWORDS * 8)   // 2 MiB

__global__ void init_ws(double* acc, unsigned* flags) {
    int i = threadIdx.x;
    if (i == 0) *acc = 0.0;
    if (i < 128) flags[i] = 0u;
}

__global__ void build_tgt_bits(const int* __restrict__ tgt,
                               uint64_t* __restrict__ bits,
                               unsigned* __restrict__ present) {
    int row = blockIdx.x;                // 0..B*H-1
    int b = row >> 9, y = row & (HH - 1);
    int x = threadIdx.x;                 // 0..511
    int t = tgt[((size_t)(b * HH + y)) * WW + x];
    int wv = x >> 6;
    bool l0 = (x & 63) == 0;
#pragma unroll
    for (int c = 0; c < CC; ++c) {
        uint64_t m = __ballot(t == c);
        if (l0) {
            bits[(((size_t)c * BB + b) * HH + y) * NWORDS + wv] = m;
            if (m) atomicOr(&present[c * BB + b], 1u);
        }
    }
}

__global__ void build_pred_bits(const float* __restrict__ pred,
                                uint64_t* __restrict__ ppos,
                                uint64_t* __restrict__ pneg,
                                unsigned* __restrict__ pnz) {
    int row = blockIdx.x;
    int b = row >> 9, y = row & (HH - 1);
    int x = threadIdx.x;
    size_t i0 = (((size_t)b * CC) * HH + y) * (size_t)WW + x;
    float a0 = pred[i0];
    float a1 = pred[i0 + (size_t)HW];
    float a2 = pred[i0 + 2 * (size_t)HW];
    float a3 = pred[i0 + 3 * (size_t)HW];
    float m = fmaxf(fmaxf(a0, a1), fmaxf(a2, a3));
    float e0 = expf(a0 - m), e1 = expf(a1 - m), e2 = expf(a2 - m), e3 = expf(a3 - m);
    float s = (e0 + e1) + (e2 + e3);
    float p0 = e0 / s, p1 = e1 / s, p2 = e2 / s, p3 = e3 / s;
    int wv = x >> 6;
    bool l0 = (x & 63) == 0;
#define EMIT(cidx, pv)                                                        \
    {                                                                         \
        uint64_t mp = __ballot((pv) == 1.0f);                                 \
        uint64_t mn = __ballot((pv) == 0.0f);                                 \
        uint64_t nz = __ballot((pv) != 0.0f);                                 \
        if (l0) {                                                             \
            size_t o = (((size_t)(cidx) * BB + b) * HH + y) * NWORDS + wv;    \
            ppos[o] = mp;                                                     \
            pneg[o] = mn;                                                     \
            if (nz) atomicOr(&pnz[(cidx) * BB + b], 1u);                      \
        }                                                                     \
    }
    EMIT(0, p0)
    EMIT(1, p1)
    EMIT(2, p2)
    EMIT(3, p3)
#undef EMIT
}

// Extract 11-bit window (dx=-5..+5 -> bits 0..10) around column x from a
// 10-word padded row (word 0 and 9 are zero pads). p = (x&63) + 59.
__device__ __forceinline__ unsigned win11(const uint64_t* row10, int idx, int p) {
    uint64_t w;
    if (p < 64) {
        w = (row10[idx] >> p) | (row10[idx + 1] << (64 - p));
    } else {
        int q = p - 64;
        uint64_t M = row10[idx + 1];
        w = q ? ((M >> q) | (row10[idx + 2] << (64 - q))) : M;
    }
    return (unsigned)w & 0x7FFu;
}

__device__ __forceinline__ void upd(int& mind2, unsigned wbits, int dy2) {
    if (wbits) {
        unsigned hi = wbits >> 5;   // bit k -> dx = k   (k=0..5)
        unsigned lo = wbits & 31u;  // bit j -> dx = j-5 (j=0..4), |dx| = 5-j
        int mdx = 6;
        if (hi) mdx = __ffs(hi) - 1;
        if (lo) {
            int m2 = 5 - (31 - __clz(lo));
            mdx = min(mdx, m2);
        }
        int cand = dy2 + mdx * mdx;
        mind2 = min(mind2, cand);
    }
}

__launch_bounds__(512)
__global__ void edt_loss_kernel(const uint64_t* __restrict__ tgtb,
                                const uint64_t* __restrict__ pposb,
                                const uint64_t* __restrict__ pnegb,
                                const unsigned* __restrict__ flags,
                                double* __restrict__ acc) {
    __shared__ uint64_t sh[3][11][10];
    __shared__ float wsum[8];

    int blk = blockIdx.x;            // ((c*BB + b)*HH + y)
    int y  = blk & (HH - 1);
    int cb = blk >> 9;
    int b  = cb & (BB - 1);
    int c  = cb >> 4;

    for (int t = threadIdx.x; t < 330; t += blockDim.x) {
        int m = t / 110;
        int rem = t - m * 110;
        int r = rem / 10;
        int wi = rem - r * 10;
        int rowy = y + r - 5;
        uint64_t v = 0;
        if (wi >= 1 && wi <= 8 && rowy >= 0 && rowy < HH) {
            const uint64_t* src = (m == 0) ? tgtb : (m == 1) ? pposb : pnegb;
            v = src[(((size_t)c * BB + b) * HH + rowy) * NWORDS + (wi - 1)];
        }
        sh[m][r][wi] = v;
    }
    __syncthreads();

    int x = threadIdx.x;
    int idx = x >> 6, off = x & 63, p = off + 59;

    unsigned vmask = 0x7FFu;                       // which dx are inside [0,W)
    if (x < 5) vmask &= (0x7FFu << (5 - x)) & 0x7FFu;
    if (x > WW - 6) vmask &= 0x7FFu >> (x - (WW - 6));

    int tp = 26, tn = 26, qp = 26, qn = 26;        // min d^2 (26 = "none found")
#pragma unroll
    for (int dy = -5; dy <= 5; ++dy) {
        int ady = dy < 0 ? -dy : dy;
        unsigned allowed = (ady == 0) ? 0x7FFu
                         : (ady <= 3) ? 0x3FEu
                         : (ady == 4) ? 0x1FCu
                                      : 0x020u;
        int dy2 = dy * dy;
        int r = dy + 5;
        unsigned wt  = win11(&sh[0][r][0], idx, p);
        unsigned wpp = win11(&sh[1][r][0], idx, p);
        unsigned wpn = win11(&sh[2][r][0], idx, p);
        upd(tp, wt & allowed, dy2);
        upd(tn, (~wt) & vmask & allowed, dy2);
        upd(qp, wpp & allowed, dy2);
        upd(qn, wpn & allowed, dy2);
    }

    float dtp = (tp <= 25) ? sqrtf((float)tp) : 5.0f;
    float dtn = (tn <= 25) ? sqrtf((float)tn) : 5.0f;
    float dqp = (qp <= 25) ? sqrtf((float)qp) : 5.0f;
    float dqn = (qn <= 25) ? sqrtf((float)qn) : 5.0f;

    float td = fminf(fmaxf(dtp - dtn, -5.0f), 5.0f) / 5.0f;
    float qd = fminf(fmaxf(dqp - dqn, -5.0f), 5.0f) / 5.0f;
    float tsdf = flags[c * BB + b] ? td : 3.0f;
    float psdf = flags[64 + c * BB + b] ? qd : 3.0f;
    float v = fabsf(psdf - tsdf);

    // wave64 shuffle reduce, then cross-wave via LDS, one f64 atomic per block
    for (int o2 = 32; o2 > 0; o2 >>= 1) v += __shfl_down(v, o2, 64);
    if (off == 0) wsum[idx] = v;
    __syncthreads();
    if (threadIdx.x == 0) {
        float s = 0.f;
#pragma unroll
        for (int i = 0; i < 8; ++i) s += wsum[i];
        atomicAdd(acc, (double)s);
    }
}

__global__ void finalize_kernel(const double* __restrict__ acc, float* __restrict__ out) {
    // loss = total / (B*H*W) / C  = total / 16777216
    out[0] = (float)(acc[0] / 16777216.0);
}

extern "C" void kernel_launch(void* const* d_in, const int* in_sizes, int n_in,
                              void* d_out, int out_size, void* d_ws, size_t ws_size,
                              hipStream_t stream) {
    const float* pred  = (const float*)d_in[0];
    const int* target  = (const int*)d_in[1];
    float* out = (float*)d_out;

    char* ws = (char*)d_ws;
    double*   acc   = (double*)ws;
    unsigned* flags = (unsigned*)(ws + OFF_FLAGS);          // 128 words
    uint64_t* tgtb  = (uint64_t*)(ws + OFF_TGT);
    uint64_t* pposb = (uint64_t*)(ws + OFF_TGT + (size_t)BOARD_BYTES);
    uint64_t* pnegb = (uint64_t*)(ws + OFF_TGT + 2 * (size_t)BOARD_BYTES);

    hipLaunchKernelGGL(init_ws, dim3(1), dim3(128), 0, stream, acc, flags);
    hipLaunchKernelGGL(build_tgt_bits, dim3(BB * HH), dim3(512), 0, stream,
                       target, tgtb, flags);
    hipLaunchKernelGGL(build_pred_bits, dim3(BB * HH), dim3(512), 0, stream,
                       pred, pposb, pnegb, flags + 64);
    hipLaunchKernelGGL(edt_loss_kernel, dim3(CC * BB * HH), dim3(512), 0, stream,
                       tgtb, pposb, pnegb, flags, acc);
    hipLaunchKernelGGL(finalize_kernel, dim3(1), dim3(1), 0, stream, acc, out);
}

// Round 2
// 548.428 us; speedup vs baseline: 4.3302x; 4.3302x over previous
//
#include <hip/hip_runtime.h>
#include <stdint.h>

#define BB 16
#define CC 4
#define HH 512
#define WW 512
#define NWORDS 8          // 512 / 64
#define HW (HH * WW)

// ---------------- ws layout ----------------
// [0]                 : double acc
// [64 .. 64+512)      : unsigned flags[128]  (0..63 tgt_present[c*16+b], 64..127 pred_nonzero)
// [4096 .. +2MB)      : u64 tgt_bits [C][B][H][NWORDS]
// [+2MB .. +4MB)      : u64 ppos_bits[C][B][H][NWORDS]  (p==1.0)
// [+4MB .. +6MB)      : u64 pneg_bits[C][B][H][NWORDS]  (p==0.0)
#define OFF_FLAGS 64
#define OFF_TGT   4096
#define BOARD_BYTES (CC * BB * HH * NWORDS * 8)   // 2 MiB

__global__ void init_ws(double* acc) {
    if (threadIdx.x == 0) *acc = 0.0;
}

__global__ void build_tgt_bits(const int* __restrict__ tgt,
                               uint64_t* __restrict__ bits) {
    int row = blockIdx.x;                // 0..B*H-1
    int b = row >> 9, y = row & (HH - 1);
    int x = threadIdx.x;                 // 0..511
    int t = tgt[((size_t)(b * HH + y)) * WW + x];
    int wv = x >> 6;
    bool l0 = (x & 63) == 0;
#pragma unroll
    for (int c = 0; c < CC; ++c) {
        uint64_t m = __ballot(t == c);
        if (l0) bits[(((size_t)c * BB + b) * HH + y) * NWORDS + wv] = m;
    }
}

__global__ void build_pred_bits(const float* __restrict__ pred,
                                uint64_t* __restrict__ ppos,
                                uint64_t* __restrict__ pneg) {
    int row = blockIdx.x;
    int b = row >> 9, y = row & (HH - 1);
    int x = threadIdx.x;
    size_t i0 = (((size_t)b * CC) * HH + y) * (size_t)WW + x;
    float a0 = pred[i0];
    float a1 = pred[i0 + (size_t)HW];
    float a2 = pred[i0 + 2 * (size_t)HW];
    float a3 = pred[i0 + 3 * (size_t)HW];
    float m = fmaxf(fmaxf(a0, a1), fmaxf(a2, a3));
    float e0 = expf(a0 - m), e1 = expf(a1 - m), e2 = expf(a2 - m), e3 = expf(a3 - m);
    float s = (e0 + e1) + (e2 + e3);
    float p0 = e0 / s, p1 = e1 / s, p2 = e2 / s, p3 = e3 / s;
    int wv = x >> 6;
    bool l0 = (x & 63) == 0;
#define EMIT(cidx, pv)                                                        \
    {                                                                         \
        uint64_t mp = __ballot((pv) == 1.0f);                                 \
        uint64_t mn = __ballot((pv) == 0.0f);                                 \
        if (l0) {                                                             \
            size_t o = (((size_t)(cidx) * BB + b) * HH + y) * NWORDS + wv;    \
            ppos[o] = mp;                                                     \
            pneg[o] = mn;                                                     \
        }                                                                     \
    }
    EMIT(0, p0)
    EMIT(1, p1)
    EMIT(2, p2)
    EMIT(3, p3)
#undef EMIT
}

// One block per (c,b): tgt_present = OR(tgt board) != 0;
// pred_nonzero = AND(pneg board) != ~0 (some pixel has p != 0).
__global__ void flags_kernel(const uint64_t* __restrict__ tgtb,
                             const uint64_t* __restrict__ pnegb,
                             unsigned* __restrict__ flags) {
    int cb = blockIdx.x;                          // 0..63  (c*BB + b)
    const uint64_t* t = tgtb + (size_t)cb * HH * NWORDS;
    const uint64_t* n = pnegb + (size_t)cb * HH * NWORDS;
    uint64_t o = 0ull, a = ~0ull;
    for (int i = threadIdx.x; i < HH * NWORDS; i += blockDim.x) {
        o |= t[i];
        a &= n[i];
    }
    for (int s = 32; s > 0; s >>= 1) {
        o |= (uint64_t)__shfl_down((unsigned long long)o, s, 64);
        a &= (uint64_t)__shfl_down((unsigned long long)a, s, 64);
    }
    __shared__ uint64_t so[4], sa[4];
    int w = threadIdx.x >> 6;
    if ((threadIdx.x & 63) == 0) { so[w] = o; sa[w] = a; }
    __syncthreads();
    if (threadIdx.x == 0) {
        uint64_t O = (so[0] | so[1]) | (so[2] | so[3]);
        uint64_t A = (sa[0] & sa[1]) & (sa[2] & sa[3]);
        flags[cb]      = (O != 0ull)  ? 1u : 0u;
        flags[64 + cb] = (A != ~0ull) ? 1u : 0u;
    }
}

// Extract 11-bit window (dx=-5..+5 -> bits 0..10) around column x from a
// 10-word padded row (word 0 and 9 are zero pads). p = (x&63) + 59.
__device__ __forceinline__ unsigned win11(const uint64_t* row10, int idx, int p) {
    uint64_t w;
    if (p < 64) {
        w = (row10[idx] >> p) | (row10[idx + 1] << (64 - p));
    } else {
        int q = p - 64;
        uint64_t M = row10[idx + 1];
        w = q ? ((M >> q) | (row10[idx + 2] << (64 - q))) : M;
    }
    return (unsigned)w & 0x7FFu;
}

__device__ __forceinline__ void upd(int& mind2, unsigned wbits, int dy2) {
    if (wbits) {
        unsigned hi = wbits >> 5;   // bit k -> dx = k   (k=0..5)
        unsigned lo = wbits & 31u;  // bit j -> dx = j-5 (j=0..4), |dx| = 5-j
        int mdx = 6;
        if (hi) mdx = __ffs(hi) - 1;
        if (lo) {
            int m2 = 5 - (31 - __clz(lo));
            mdx = min(mdx, m2);
        }
        int cand = dy2 + mdx * mdx;
        mind2 = min(mind2, cand);
    }
}

__launch_bounds__(512)
__global__ void edt_loss_kernel(const uint64_t* __restrict__ tgtb,
                                const uint64_t* __restrict__ pposb,
                                const uint64_t* __restrict__ pnegb,
                                const unsigned* __restrict__ flags,
                                double* __restrict__ acc) {
    __shared__ uint64_t sh[3][11][10];
    __shared__ float wsum[8];

    int blk = blockIdx.x;            // ((c*BB + b)*HH + y)
    int y  = blk & (HH - 1);
    int cb = blk >> 9;
    int b  = cb & (BB - 1);
    int c  = cb >> 4;

    for (int t = threadIdx.x; t < 330; t += blockDim.x) {
        int m = t / 110;
        int rem = t - m * 110;
        int r = rem / 10;
        int wi = rem - r * 10;
        int rowy = y + r - 5;
        uint64_t v = 0;
        if (wi >= 1 && wi <= 8 && rowy >= 0 && rowy < HH) {
            const uint64_t* src = (m == 0) ? tgtb : (m == 1) ? pposb : pnegb;
            v = src[(((size_t)c * BB + b) * HH + rowy) * NWORDS + (wi - 1)];
        }
        sh[m][r][wi] = v;
    }
    __syncthreads();

    int x = threadIdx.x;
    int idx = x >> 6, off = x & 63, p = off + 59;

    unsigned vmask = 0x7FFu;                       // which dx are inside [0,W)
    if (x < 5) vmask &= (0x7FFu << (5 - x)) & 0x7FFu;
    if (x > WW - 6) vmask &= 0x7FFu >> (x - (WW - 6));

    int tp = 26, tn = 26, qp = 26, qn = 26;        // min d^2 (26 = "none found")
#pragma unroll
    for (int dy = -5; dy <= 5; ++dy) {
        int ady = dy < 0 ? -dy : dy;
        unsigned allowed = (ady == 0) ? 0x7FFu
                         : (ady <= 3) ? 0x3FEu
                         : (ady == 4) ? 0x1FCu
                                      : 0x020u;
        int dy2 = dy * dy;
        int r = dy + 5;
        unsigned wt  = win11(&sh[0][r][0], idx, p);
        unsigned wpp = win11(&sh[1][r][0], idx, p);
        unsigned wpn = win11(&sh[2][r][0], idx, p);
        upd(tp, wt & allowed, dy2);
        upd(tn, (~wt) & vmask & allowed, dy2);
        upd(qp, wpp & allowed, dy2);
        upd(qn, wpn & allowed, dy2);
    }

    float dtp = (tp <= 25) ? sqrtf((float)tp) : 5.0f;
    float dtn = (tn <= 25) ? sqrtf((float)tn) : 5.0f;
    float dqp = (qp <= 25) ? sqrtf((float)qp) : 5.0f;
    float dqn = (qn <= 25) ? sqrtf((float)qn) : 5.0f;

    float td = fminf(fmaxf(dtp - dtn, -5.0f), 5.0f) / 5.0f;
    float qd = fminf(fmaxf(dqp - dqn, -5.0f), 5.0f) / 5.0f;
    float tsdf = flags[c * BB + b] ? td : 3.0f;
    float psdf = flags[64 + c * BB + b] ? qd : 3.0f;
    float v = fabsf(psdf - tsdf);

    // wave64 shuffle reduce, then cross-wave via LDS, one f64 atomic per block
    for (int o2 = 32; o2 > 0; o2 >>= 1) v += __shfl_down(v, o2, 64);
    if (off == 0) wsum[idx] = v;
    __syncthreads();
    if (threadIdx.x == 0) {
        float s = 0.f;
#pragma unroll
        for (int i = 0; i < 8; ++i) s += wsum[i];
        atomicAdd(acc, (double)s);
    }
}

__global__ void finalize_kernel(const double* __restrict__ acc, float* __restrict__ out) {
    // loss = total / (B*H*W) / C  = total / 16777216
    out[0] = (float)(acc[0] / 16777216.0);
}

extern "C" void kernel_launch(void* const* d_in, const int* in_sizes, int n_in,
                              void* d_out, int out_size, void* d_ws, size_t ws_size,
                              hipStream_t stream) {
    const float* pred  = (const float*)d_in[0];
    const int* target  = (const int*)d_in[1];
    float* out = (float*)d_out;

    char* ws = (char*)d_ws;
    double*   acc   = (double*)ws;
    unsigned* flags = (unsigned*)(ws + OFF_FLAGS);          // 128 words
    uint64_t* tgtb  = (uint64_t*)(ws + OFF_TGT);
    uint64_t* pposb = (uint64_t*)(ws + OFF_TGT + (size_t)BOARD_BYTES);
    uint64_t* pnegb = (uint64_t*)(ws + OFF_TGT + 2 * (size_t)BOARD_BYTES);

    hipLaunchKernelGGL(init_ws, dim3(1), dim3(64), 0, stream, acc);
    hipLaunchKernelGGL(build_tgt_bits, dim3(BB * HH), dim3(512), 0, stream,
                       target, tgtb);
    hipLaunchKernelGGL(build_pred_bits, dim3(BB * HH), dim3(512), 0, stream,
                       pred, pposb, pnegb);
    hipLaunchKernelGGL(flags_kernel, dim3(CC * BB), dim3(256), 0, stream,
                       tgtb, pnegb, flags);
    hipLaunchKernelGGL(edt_loss_kernel, dim3(CC * BB * HH), dim3(512), 0, stream,
                       tgtb, pposb, pnegb, flags, acc);
    hipLaunchKernelGGL(finalize_kernel, dim3(1), dim3(1), 0, stream, acc, out);
}

// Round 3
// 155.159 us; speedup vs baseline: 15.3054x; 3.5346x over previous
//
#include <hip/hip_runtime.h>
#include <stdint.h>

#define BB 16
#define CC 4
#define HH 512
#define WW 512
#define NWORDS 8          // 512 / 64
#define HW (HH * WW)

// ---------------- ws layout ----------------
// [0]        : double acc
// [64]       : unsigned flags[128] (0..63 tgt_present[cb], 64..127 pred_nonzero)
// [1024]     : unsigned mode[64]   (1 = fast path valid for this (c,b))
// [4096]     : u64 tgt_bits [C][B][H][NWORDS]
// [+2MB]     : u64 ppos_bits[C][B][H][NWORDS]  (p==1.0)
// [+4MB]     : u64 pneg_bits[C][B][H][NWORDS]  (p==0.0)
#define OFF_FLAGS 64
#define OFF_MODE  1024
#define OFF_TGT   4096
#define BOARD_BYTES (CC * BB * HH * NWORDS * 8)   // 2 MiB

__global__ void init_ws(double* acc) {
    if (threadIdx.x == 0) *acc = 0.0;
}

__global__ void build_tgt_bits(const int* __restrict__ tgt,
                               uint64_t* __restrict__ bits) {
    int row = blockIdx.x;                // 0..B*H-1
    int b = row >> 9, y = row & (HH - 1);
    int x = threadIdx.x;                 // 0..511
    int t = tgt[((size_t)(b * HH + y)) * WW + x];
    int wv = x >> 6;
    bool l0 = (x & 63) == 0;
#pragma unroll
    for (int c = 0; c < CC; ++c) {
        uint64_t m = __ballot(t == c);
        if (l0) bits[(((size_t)c * BB + b) * HH + y) * NWORDS + wv] = m;
    }
}

__global__ void build_pred_bits(const float* __restrict__ pred,
                                uint64_t* __restrict__ ppos,
                                uint64_t* __restrict__ pneg) {
    int row = blockIdx.x;
    int b = row >> 9, y = row & (HH - 1);
    int x = threadIdx.x;
    size_t i0 = (((size_t)b * CC) * HH + y) * (size_t)WW + x;
    float a0 = pred[i0];
    float a1 = pred[i0 + (size_t)HW];
    float a2 = pred[i0 + 2 * (size_t)HW];
    float a3 = pred[i0 + 3 * (size_t)HW];
    float m = fmaxf(fmaxf(a0, a1), fmaxf(a2, a3));
    float e0 = expf(a0 - m), e1 = expf(a1 - m), e2 = expf(a2 - m), e3 = expf(a3 - m);
    float s = (e0 + e1) + (e2 + e3);
    float p0 = e0 / s, p1 = e1 / s, p2 = e2 / s, p3 = e3 / s;
    int wv = x >> 6;
    bool l0 = (x & 63) == 0;
#define EMIT(cidx, pv)                                                        \
    {                                                                         \
        uint64_t mp = __ballot((pv) == 1.0f);                                 \
        uint64_t mn = __ballot((pv) == 0.0f);                                 \
        if (l0) {                                                             \
            size_t o = (((size_t)(cidx) * BB + b) * HH + y) * NWORDS + wv;    \
            ppos[o] = mp;                                                     \
            pneg[o] = mn;                                                     \
        }                                                                     \
    }
    EMIT(0, p0)
    EMIT(1, p1)
    EMIT(2, p2)
    EMIT(3, p3)
#undef EMIT
}

// One block per (c,b). Computes tgt_present, pred_nonzero, and whether the
// word-parallel fast path applies (both pred sets empty -> psdf == 0).
// Also adds the constant contribution for (fast && target empty): 3 * HW.
__global__ void flags_kernel(const uint64_t* __restrict__ tgtb,
                             const uint64_t* __restrict__ pposb,
                             const uint64_t* __restrict__ pnegb,
                             unsigned* __restrict__ flags,
                             unsigned* __restrict__ mode,
                             double* __restrict__ acc) {
    int cb = blockIdx.x;                          // 0..63  (c*BB + b)
    const uint64_t* t  = tgtb  + (size_t)cb * HH * NWORDS;
    const uint64_t* pp = pposb + (size_t)cb * HH * NWORDS;
    const uint64_t* pn = pnegb + (size_t)cb * HH * NWORDS;
    uint64_t ot = 0ull, op = 0ull, on = 0ull, an = ~0ull;
    for (int i = threadIdx.x; i < HH * NWORDS; i += blockDim.x) {
        ot |= t[i];
        op |= pp[i];
        uint64_t v = pn[i];
        on |= v;
        an &= v;
    }
    for (int s = 32; s > 0; s >>= 1) {
        ot |= (uint64_t)__shfl_down((unsigned long long)ot, s, 64);
        op |= (uint64_t)__shfl_down((unsigned long long)op, s, 64);
        on |= (uint64_t)__shfl_down((unsigned long long)on, s, 64);
        an &= (uint64_t)__shfl_down((unsigned long long)an, s, 64);
    }
    __shared__ uint64_t sot[4], sop[4], son[4], san[4];
    int wv = threadIdx.x >> 6;
    if ((threadIdx.x & 63) == 0) { sot[wv]=ot; sop[wv]=op; son[wv]=on; san[wv]=an; }
    __syncthreads();
    if (threadIdx.x == 0) {
        uint64_t OT = (sot[0]|sot[1])|(sot[2]|sot[3]);
        uint64_t OP = (sop[0]|sop[1])|(sop[2]|sop[3]);
        uint64_t ON = (son[0]|son[1])|(son[2]|son[3]);
        uint64_t AN = (san[0]&san[1])&(san[2]&san[3]);
        unsigned present = (OT != 0ull)  ? 1u : 0u;
        unsigned prednz  = (AN != ~0ull) ? 1u : 0u;
        unsigned fast    = (OP == 0ull && ON == 0ull) ? 1u : 0u;
        flags[cb]      = present;
        flags[64 + cb] = prednz;
        mode[cb]       = fast;
        if (fast && !present) atomicAdd(acc, 3.0 * (double)HW);
    }
}

__device__ __forceinline__ constexpr int lev_idx(int d2) {
    return d2==0?0: d2==1?1: d2==2?2: d2==4?3: d2==5?4: d2==8?5: d2==9?6:
           d2==10?7: d2==13?8: d2==16?9: d2==17?10: d2==18?11: d2==20?12: 13;
}

// Word-parallel EDT level-set sum. Valid when psdf == 0 uniformly:
// sum over pixels of |tsdf| = (sum dtp + sum dtn) / 5, computed by
// incremental disk dilation of T and ~T with popcounts per d^2 level.
// One block per (cb, 64-row tile).
__launch_bounds__(512)
__global__ void fast_edt_sum(const uint64_t* __restrict__ tgtb,
                             const unsigned* __restrict__ flags,
                             const unsigned* __restrict__ mode,
                             double* __restrict__ acc) {
    int blk  = blockIdx.x;
    int tile = blk & 7;
    int cb   = blk >> 3;
    if (!mode[cb] || !flags[cb]) return;   // fallback kernel / flags handle these

    __shared__ uint64_t sT[74][8];
    __shared__ float wsum[8];
    const uint64_t* board = tgtb + (size_t)cb * HH * NWORDS;
    int y0 = tile * 64;
    for (int t = threadIdx.x; t < 74 * 8; t += 512) {
        int r = t >> 3, w = t & 7;
        int yy = y0 + r - 5;
        sT[r][w] = (yy >= 0 && yy < HH) ? board[(size_t)yy * NWORDS + w] : 0ull;
    }
    __syncthreads();

    int tr = threadIdx.x >> 3;    // row within tile (0..63)
    int w  = threadIdx.x & 7;     // word column (0..7)
    int y  = y0 + tr;

    uint64_t DT[14], DC[14];
#pragma unroll
    for (int k = 0; k < 14; ++k) { DT[k] = 0ull; DC[k] = 0ull; }

#pragma unroll
    for (int dy = -5; dy <= 5; ++dy) {
        int yy = y + dy;
        if (yy < 0 || yy >= HH) continue;       // row outside: neither board has bits
        const int ady  = dy < 0 ? -dy : dy;
        const int maxs = (ady == 0) ? 5 : (ady <= 3) ? 4 : (ady == 4) ? 3 : 0;
        int ly = tr + 5 + dy;
        uint64_t Cw = sT[ly][w];
        uint64_t Lw = (w > 0) ? sT[ly][w - 1] : 0ull;
        uint64_t Rw = (w < 7) ? sT[ly][w + 1] : 0ull;
        uint64_t Cc = ~Cw;
        uint64_t Lc = (w > 0) ? ~Lw : 0ull;     // outside image is NOT in complement
        uint64_t Rc = (w < 7) ? ~Rw : 0ull;
        uint64_t UT = Cw, UC = Cc;
        DT[lev_idx(ady * ady)] |= UT;
        DC[lev_idx(ady * ady)] |= UC;
#pragma unroll
        for (int s = 1; s <= 5; ++s) {
            if (s > maxs) break;                // folds at compile time (ady const)
            UT |= (Cw >> s) | (Rw << (64 - s)) | (Cw << s) | (Lw >> (64 - s));
            UC |= (Cc >> s) | (Rc << (64 - s)) | (Cc << s) | (Lc >> (64 - s));
            const int li = lev_idx(ady * ady + s * s);
            DT[li] |= UT;
            DC[li] |= UC;
        }
    }

    const float dist[14] = {0.f, 1.f, 1.41421356f, 2.f, 2.23606798f,
        2.82842712f, 3.f, 3.16227766f, 3.60555128f, 4.f, 4.12310563f,
        4.24264069f, 4.47213595f, 5.f};
    uint64_t covT = 0ull, covC = 0ull;
    float s = 0.f;
#pragma unroll
    for (int k = 0; k < 14; ++k) {
        uint64_t nT = DT[k] & ~covT;
        uint64_t nC = DC[k] & ~covC;
        s += dist[k] * (float)(__popcll(nT) + __popcll(nC));
        covT |= DT[k];
        covC |= DC[k];
    }
    s += 5.f * (float)(__popcll(~covT) + __popcll(~covC));   // capped pixels

    for (int o = 32; o > 0; o >>= 1) s += __shfl_down(s, o, 64);
    if ((threadIdx.x & 63) == 0) wsum[threadIdx.x >> 6] = s;
    __syncthreads();
    if (threadIdx.x == 0) {
        float tot = 0.f;
#pragma unroll
        for (int i = 0; i < 8; ++i) tot += wsum[i];
        atomicAdd(acc, (double)tot * 0.2);      // /5
    }
}

// ---------- general per-pixel fallback (runs only where mode==0) ----------
__device__ __forceinline__ unsigned win11(const uint64_t* row10, int idx, int p) {
    uint64_t w;
    if (p < 64) {
        w = (row10[idx] >> p) | (row10[idx + 1] << (64 - p));
    } else {
        int q = p - 64;
        uint64_t M = row10[idx + 1];
        w = q ? ((M >> q) | (row10[idx + 2] << (64 - q))) : M;
    }
    return (unsigned)w & 0x7FFu;
}

__device__ __forceinline__ void upd(int& mind2, unsigned wbits, int dy2) {
    if (wbits) {
        unsigned hi = wbits >> 5;
        unsigned lo = wbits & 31u;
        int mdx = 6;
        if (hi) mdx = __ffs(hi) - 1;
        if (lo) {
            int m2 = 5 - (31 - __clz(lo));
            mdx = min(mdx, m2);
        }
        int cand = dy2 + mdx * mdx;
        mind2 = min(mind2, cand);
    }
}

__launch_bounds__(512)
__global__ void edt_loss_kernel(const uint64_t* __restrict__ tgtb,
                                const uint64_t* __restrict__ pposb,
                                const uint64_t* __restrict__ pnegb,
                                const unsigned* __restrict__ flags,
                                const unsigned* __restrict__ mode,
                                double* __restrict__ acc) {
    int blk = blockIdx.x;            // ((c*BB + b)*HH + y)
    int cb = blk >> 9;
    if (mode[cb]) return;            // fast path already handled this (c,b)

    __shared__ uint64_t sh[3][11][10];
    __shared__ float wsum[8];
    int y = blk & (HH - 1);
    int b = cb & (BB - 1);
    int c = cb >> 4;

    for (int t = threadIdx.x; t < 330; t += blockDim.x) {
        int m = t / 110;
        int rem = t - m * 110;
        int r = rem / 10;
        int wi = rem - r * 10;
        int rowy = y + r - 5;
        uint64_t v = 0;
        if (wi >= 1 && wi <= 8 && rowy >= 0 && rowy < HH) {
            const uint64_t* src = (m == 0) ? tgtb : (m == 1) ? pposb : pnegb;
            v = src[(((size_t)c * BB + b) * HH + rowy) * NWORDS + (wi - 1)];
        }
        sh[m][r][wi] = v;
    }
    __syncthreads();

    int x = threadIdx.x;
    int idx = x >> 6, off = x & 63, p = off + 59;

    unsigned vmask = 0x7FFu;
    if (x < 5) vmask &= (0x7FFu << (5 - x)) & 0x7FFu;
    if (x > WW - 6) vmask &= 0x7FFu >> (x - (WW - 6));

    int tp = 26, tn = 26, qp = 26, qn = 26;
#pragma unroll
    for (int dy = -5; dy <= 5; ++dy) {
        int ady = dy < 0 ? -dy : dy;
        unsigned allowed = (ady == 0) ? 0x7FFu
                         : (ady <= 3) ? 0x3FEu
                         : (ady == 4) ? 0x1FCu
                                      : 0x020u;
        int dy2 = dy * dy;
        int r = dy + 5;
        unsigned wt  = win11(&sh[0][r][0], idx, p);
        unsigned wpp = win11(&sh[1][r][0], idx, p);
        unsigned wpn = win11(&sh[2][r][0], idx, p);
        upd(tp, wt & allowed, dy2);
        upd(tn, (~wt) & vmask & allowed, dy2);
        upd(qp, wpp & allowed, dy2);
        upd(qn, wpn & allowed, dy2);
    }

    float dtp = (tp <= 25) ? sqrtf((float)tp) : 5.0f;
    float dtn = (tn <= 25) ? sqrtf((float)tn) : 5.0f;
    float dqp = (qp <= 25) ? sqrtf((float)qp) : 5.0f;
    float dqn = (qn <= 25) ? sqrtf((float)qn) : 5.0f;

    float td = fminf(fmaxf(dtp - dtn, -5.0f), 5.0f) / 5.0f;
    float qd = fminf(fmaxf(dqp - dqn, -5.0f), 5.0f) / 5.0f;
    float tsdf = flags[cb] ? td : 3.0f;
    float psdf = flags[64 + cb] ? qd : 3.0f;
    float v = fabsf(psdf - tsdf);

    for (int o2 = 32; o2 > 0; o2 >>= 1) v += __shfl_down(v, o2, 64);
    if (off == 0) wsum[idx] = v;
    __syncthreads();
    if (threadIdx.x == 0) {
        float s = 0.f;
#pragma unroll
        for (int i = 0; i < 8; ++i) s += wsum[i];
        atomicAdd(acc, (double)s);
    }
}

__global__ void finalize_kernel(const double* __restrict__ acc, float* __restrict__ out) {
    out[0] = (float)(acc[0] / 16777216.0);   // / (B*H*W*C)
}

extern "C" void kernel_launch(void* const* d_in, const int* in_sizes, int n_in,
                              void* d_out, int out_size, void* d_ws, size_t ws_size,
                              hipStream_t stream) {
    const float* pred  = (const float*)d_in[0];
    const int* target  = (const int*)d_in[1];
    float* out = (float*)d_out;

    char* ws = (char*)d_ws;
    double*   acc   = (double*)ws;
    unsigned* flags = (unsigned*)(ws + OFF_FLAGS);
    unsigned* mode  = (unsigned*)(ws + OFF_MODE);
    uint64_t* tgtb  = (uint64_t*)(ws + OFF_TGT);
    uint64_t* pposb = (uint64_t*)(ws + OFF_TGT + (size_t)BOARD_BYTES);
    uint64_t* pnegb = (uint64_t*)(ws + OFF_TGT + 2 * (size_t)BOARD_BYTES);

    hipLaunchKernelGGL(init_ws, dim3(1), dim3(64), 0, stream, acc);
    hipLaunchKernelGGL(build_tgt_bits, dim3(BB * HH), dim3(512), 0, stream,
                       target, tgtb);
    hipLaunchKernelGGL(build_pred_bits, dim3(BB * HH), dim3(512), 0, stream,
                       pred, pposb, pnegb);
    hipLaunchKernelGGL(flags_kernel, dim3(CC * BB), dim3(256), 0, stream,
                       tgtb, pposb, pnegb, flags, mode, acc);
    hipLaunchKernelGGL(fast_edt_sum, dim3(CC * BB * 8), dim3(512), 0, stream,
                       tgtb, flags, mode, acc);
    hipLaunchKernelGGL(edt_loss_kernel, dim3(CC * BB * HH), dim3(512), 0, stream,
                       tgtb, pposb, pnegb, flags, mode, acc);
    hipLaunchKernelGGL(finalize_kernel, dim3(1), dim3(1), 0, stream, acc, out);
}

// Round 4
// 132.880 us; speedup vs baseline: 17.8717x; 1.1677x over previous
//
#include <hip/hip_runtime.h>
#include <stdint.h>

#define BB 16
#define CC 4
#define HH 512
#define WW 512
#define NWORDS 8          // 512 / 64
#define HW (HH * WW)

// ---------------- ws layout ----------------
// [0]        : double acc
// [64]       : unsigned flags[128] (0..63 tgt_present[cb], 64..127 pred_nonzero)
// [1024]     : unsigned mode[64]   (1 = fast path valid for this (c,b))
// [4096]     : u64 tgt_bits [C][B][H][NWORDS]
// [+2MB]     : u64 ppos_bits[C][B][H][NWORDS]  (p==1.0)
// [+4MB]     : u64 pneg_bits[C][B][H][NWORDS]  (p==0.0)
#define OFF_FLAGS 64
#define OFF_MODE  1024
#define OFF_TGT   4096
#define BOARD_BYTES (CC * BB * HH * NWORDS * 8)   // 2 MiB

// Fused: target bitboards + softmax p==1/p==0 bitboards. Also zeroes acc
// (safe: all acc atomics happen in later stream-ordered kernels).
__global__ void build_bits(const int* __restrict__ tgt,
                           const float* __restrict__ pred,
                           uint64_t* __restrict__ tgtb,
                           uint64_t* __restrict__ ppos,
                           uint64_t* __restrict__ pneg,
                           double* __restrict__ acc) {
    int row = blockIdx.x;                // 0..B*H-1
    int b = row >> 9, y = row & (HH - 1);
    int x = threadIdx.x;                 // 0..511
    if (row == 0 && x == 0) *acc = 0.0;

    int t = tgt[((size_t)(b * HH + y)) * WW + x];
    size_t i0 = (((size_t)b * CC) * HH + y) * (size_t)WW + x;
    float a0 = pred[i0];
    float a1 = pred[i0 + (size_t)HW];
    float a2 = pred[i0 + 2 * (size_t)HW];
    float a3 = pred[i0 + 3 * (size_t)HW];
    float m = fmaxf(fmaxf(a0, a1), fmaxf(a2, a3));
    float e0 = expf(a0 - m), e1 = expf(a1 - m), e2 = expf(a2 - m), e3 = expf(a3 - m);
    float s = (e0 + e1) + (e2 + e3);
    float p0 = e0 / s, p1 = e1 / s, p2 = e2 / s, p3 = e3 / s;

    int wv = x >> 6;
    bool l0 = (x & 63) == 0;
#define EMIT(cidx, pv)                                                        \
    {                                                                         \
        uint64_t mt = __ballot(t == (cidx));                                  \
        uint64_t mp = __ballot((pv) == 1.0f);                                 \
        uint64_t mn = __ballot((pv) == 0.0f);                                 \
        if (l0) {                                                             \
            size_t o = (((size_t)(cidx) * BB + b) * HH + y) * NWORDS + wv;    \
            tgtb[o] = mt;                                                     \
            ppos[o] = mp;                                                     \
            pneg[o] = mn;                                                     \
        }                                                                     \
    }
    EMIT(0, p0)
    EMIT(1, p1)
    EMIT(2, p2)
    EMIT(3, p3)
#undef EMIT
}

// One block per (c,b). tgt_present, pred_nonzero, fast-path validity.
// Adds the constant contribution for (fast && target empty): 3 * HW.
__global__ void flags_kernel(const uint64_t* __restrict__ tgtb,
                             const uint64_t* __restrict__ pposb,
                             const uint64_t* __restrict__ pnegb,
                             unsigned* __restrict__ flags,
                             unsigned* __restrict__ mode,
                             double* __restrict__ acc) {
    int cb = blockIdx.x;                          // 0..63  (c*BB + b)
    const uint64_t* t  = tgtb  + (size_t)cb * HH * NWORDS;
    const uint64_t* pp = pposb + (size_t)cb * HH * NWORDS;
    const uint64_t* pn = pnegb + (size_t)cb * HH * NWORDS;
    uint64_t ot = 0ull, op = 0ull, on = 0ull, an = ~0ull;
    for (int i = threadIdx.x; i < HH * NWORDS; i += blockDim.x) {
        ot |= t[i];
        op |= pp[i];
        uint64_t v = pn[i];
        on |= v;
        an &= v;
    }
    for (int s = 32; s > 0; s >>= 1) {
        ot |= (uint64_t)__shfl_down((unsigned long long)ot, s, 64);
        op |= (uint64_t)__shfl_down((unsigned long long)op, s, 64);
        on |= (uint64_t)__shfl_down((unsigned long long)on, s, 64);
        an &= (uint64_t)__shfl_down((unsigned long long)an, s, 64);
    }
    __shared__ uint64_t sot[8], sop[8], son[8], san[8];
    int wv = threadIdx.x >> 6;
    if ((threadIdx.x & 63) == 0) { sot[wv]=ot; sop[wv]=op; son[wv]=on; san[wv]=an; }
    __syncthreads();
    if (threadIdx.x == 0) {
        int nw = blockDim.x >> 6;
        uint64_t OT = 0, OP = 0, ON = 0, AN = ~0ull;
        for (int i = 0; i < nw; ++i) { OT|=sot[i]; OP|=sop[i]; ON|=son[i]; AN&=san[i]; }
        unsigned present = (OT != 0ull)  ? 1u : 0u;
        unsigned prednz  = (AN != ~0ull) ? 1u : 0u;
        unsigned fast    = (OP == 0ull && ON == 0ull) ? 1u : 0u;
        flags[cb]      = present;
        flags[64 + cb] = prednz;
        mode[cb]       = fast;
        if (fast && !present) atomicAdd(acc, 3.0 * (double)HW);
    }
}

__device__ __forceinline__ constexpr int lev_idx(int d2) {
    return d2==0?0: d2==1?1: d2==2?2: d2==4?3: d2==5?4: d2==8?5: d2==9?6:
           d2==10?7: d2==13?8: d2==16?9: d2==17?10: d2==18?11: d2==20?12: 13;
}

// ---------- general per-pixel helpers (cold fallback path) ----------
__device__ __forceinline__ unsigned win11(const uint64_t* row10, int idx, int p) {
    uint64_t w;
    if (p < 64) {
        w = (row10[idx] >> p) | (row10[idx + 1] << (64 - p));
    } else {
        int q = p - 64;
        uint64_t M = row10[idx + 1];
        w = q ? ((M >> q) | (row10[idx + 2] << (64 - q))) : M;
    }
    return (unsigned)w & 0x7FFu;
}

__device__ __forceinline__ void upd(int& mind2, unsigned wbits, int dy2) {
    if (wbits) {
        unsigned hi = wbits >> 5;
        unsigned lo = wbits & 31u;
        int mdx = 6;
        if (hi) mdx = __ffs(hi) - 1;
        if (lo) {
            int m2 = 5 - (31 - __clz(lo));
            mdx = min(mdx, m2);
        }
        int cand = dy2 + mdx * mdx;
        mind2 = min(mind2, cand);
    }
}

// One block per (cb, 64-row tile). mode==1: word-parallel level-set sum.
// mode==0: general per-pixel path over the tile's 64 rows.
__launch_bounds__(512)
__global__ void edt_main(const uint64_t* __restrict__ tgtb,
                         const uint64_t* __restrict__ pposb,
                         const uint64_t* __restrict__ pnegb,
                         const unsigned* __restrict__ flags,
                         const unsigned* __restrict__ mode,
                         double* __restrict__ acc) {
    __shared__ uint64_t shm[74 * 8];     // fast: sT[74][8]; general: sh[3][11][10]
    __shared__ float wsum[8];
    int tile = blockIdx.x & 7;
    int cb   = blockIdx.x >> 3;
    int y0   = tile * 64;

    if (mode[cb]) {
        if (!flags[cb]) return;          // constant handled in flags_kernel
        uint64_t (*sT)[8] = (uint64_t (*)[8])shm;
        const uint64_t* board = tgtb + (size_t)cb * HH * NWORDS;
        for (int t = threadIdx.x; t < 74 * 8; t += 512) {
            int r = t >> 3, w = t & 7;
            int yy = y0 + r - 5;
            sT[r][w] = (yy >= 0 && yy < HH) ? board[(size_t)yy * NWORDS + w] : 0ull;
        }
        __syncthreads();

        int tr = threadIdx.x >> 3;    // row within tile (0..63)
        int w  = threadIdx.x & 7;     // word column (0..7)
        int y  = y0 + tr;

        uint64_t DT[14], DC[14];
#pragma unroll
        for (int k = 0; k < 14; ++k) { DT[k] = 0ull; DC[k] = 0ull; }

#pragma unroll
        for (int dy = -5; dy <= 5; ++dy) {
            int yy = y + dy;
            if (yy < 0 || yy >= HH) continue;
            const int ady  = dy < 0 ? -dy : dy;
            const int maxs = (ady == 0) ? 5 : (ady <= 3) ? 4 : (ady == 4) ? 3 : 0;
            int ly = tr + 5 + dy;
            uint64_t Cw = sT[ly][w];
            uint64_t Lw = (w > 0) ? sT[ly][w - 1] : 0ull;
            uint64_t Rw = (w < 7) ? sT[ly][w + 1] : 0ull;
            uint64_t Cc = ~Cw;
            uint64_t Lc = (w > 0) ? ~Lw : 0ull;   // outside image not in complement
            uint64_t Rc = (w < 7) ? ~Rw : 0ull;
            uint64_t UT = Cw, UC = Cc;
            DT[lev_idx(ady * ady)] |= UT;
            DC[lev_idx(ady * ady)] |= UC;
#pragma unroll
            for (int s = 1; s <= 5; ++s) {
                if (s > maxs) break;
                UT |= (Cw >> s) | (Rw << (64 - s)) | (Cw << s) | (Lw >> (64 - s));
                UC |= (Cc >> s) | (Rc << (64 - s)) | (Cc << s) | (Lc >> (64 - s));
                const int li = lev_idx(ady * ady + s * s);
                DT[li] |= UT;
                DC[li] |= UC;
            }
        }

        const float dist[14] = {0.f, 1.f, 1.41421356f, 2.f, 2.23606798f,
            2.82842712f, 3.f, 3.16227766f, 3.60555128f, 4.f, 4.12310563f,
            4.24264069f, 4.47213595f, 5.f};
        uint64_t covT = 0ull, covC = 0ull;
        float s = 0.f;
#pragma unroll
        for (int k = 0; k < 14; ++k) {
            uint64_t nT = DT[k] & ~covT;
            uint64_t nC = DC[k] & ~covC;
            s += dist[k] * (float)(__popcll(nT) + __popcll(nC));
            covT |= DT[k];
            covC |= DC[k];
        }
        s += 5.f * (float)(__popcll(~covT) + __popcll(~covC));

        for (int o = 32; o > 0; o >>= 1) s += __shfl_down(s, o, 64);
        if ((threadIdx.x & 63) == 0) wsum[threadIdx.x >> 6] = s;
        __syncthreads();
        if (threadIdx.x == 0) {
            float tot = 0.f;
#pragma unroll
            for (int i = 0; i < 8; ++i) tot += wsum[i];
            atomicAdd(acc, (double)tot * 0.2);      // /5
        }
        return;
    }

    // ---------- general path (cold): per-pixel over 64 rows ----------
    uint64_t (*sh)[11][10] = (uint64_t (*)[11][10])shm;
    int x = threadIdx.x;
    int idx = x >> 6, off = x & 63, p = off + 59;
    int b = cb & (BB - 1);
    int c = cb >> 4;
    unsigned fpres = flags[cb], fnz = flags[64 + cb];

    unsigned vmask = 0x7FFu;
    if (x < 5) vmask &= (0x7FFu << (5 - x)) & 0x7FFu;
    if (x > WW - 6) vmask &= 0x7FFu >> (x - (WW - 6));

    float vsum = 0.f;
    for (int yy = 0; yy < 64; ++yy) {
        int y = y0 + yy;
        __syncthreads();     // previous iteration's reads complete
        for (int t = threadIdx.x; t < 330; t += 512) {
            int m = t / 110;
            int rem = t - m * 110;
            int r = rem / 10;
            int wi = rem - r * 10;
            int rowy = y + r - 5;
            uint64_t v = 0;
            if (wi >= 1 && wi <= 8 && rowy >= 0 && rowy < HH) {
                const uint64_t* src = (m == 0) ? tgtb : (m == 1) ? pposb : pnegb;
                v = src[(((size_t)c * BB + b) * HH + rowy) * NWORDS + (wi - 1)];
            }
            sh[m][r][wi] = v;
        }
        __syncthreads();

        int tp = 26, tn = 26, qp = 26, qn = 26;
#pragma unroll
        for (int dy = -5; dy <= 5; ++dy) {
            int ady = dy < 0 ? -dy : dy;
            unsigned allowed = (ady == 0) ? 0x7FFu
                             : (ady <= 3) ? 0x3FEu
                             : (ady == 4) ? 0x1FCu
                                          : 0x020u;
            int dy2 = dy * dy;
            int r = dy + 5;
            unsigned wt  = win11(&sh[0][r][0], idx, p);
            unsigned wpp = win11(&sh[1][r][0], idx, p);
            unsigned wpn = win11(&sh[2][r][0], idx, p);
            upd(tp, wt & allowed, dy2);
            upd(tn, (~wt) & vmask & allowed, dy2);
            upd(qp, wpp & allowed, dy2);
            upd(qn, wpn & allowed, dy2);
        }

        float dtp = (tp <= 25) ? sqrtf((float)tp) : 5.0f;
        float dtn = (tn <= 25) ? sqrtf((float)tn) : 5.0f;
        float dqp = (qp <= 25) ? sqrtf((float)qp) : 5.0f;
        float dqn = (qn <= 25) ? sqrtf((float)qn) : 5.0f;

        float td = fminf(fmaxf(dtp - dtn, -5.0f), 5.0f) / 5.0f;
        float qd = fminf(fmaxf(dqp - dqn, -5.0f), 5.0f) / 5.0f;
        float tsdf = fpres ? td : 3.0f;
        float psdf = fnz ? qd : 3.0f;
        vsum += fabsf(psdf - tsdf);
    }

    for (int o2 = 32; o2 > 0; o2 >>= 1) vsum += __shfl_down(vsum, o2, 64);
    if (off == 0) wsum[idx] = vsum;
    __syncthreads();
    if (threadIdx.x == 0) {
        float s = 0.f;
#pragma unroll
        for (int i = 0; i < 8; ++i) s += wsum[i];
        atomicAdd(acc, (double)s);
    }
}

__global__ void finalize_kernel(const double* __restrict__ acc, float* __restrict__ out) {
    out[0] = (float)(acc[0] / 16777216.0);   // / (B*H*W*C)
}

extern "C" void kernel_launch(void* const* d_in, const int* in_sizes, int n_in,
                              void* d_out, int out_size, void* d_ws, size_t ws_size,
                              hipStream_t stream) {
    const float* pred  = (const float*)d_in[0];
    const int* target  = (const int*)d_in[1];
    float* out = (float*)d_out;

    char* ws = (char*)d_ws;
    double*   acc   = (double*)ws;
    unsigned* flags = (unsigned*)(ws + OFF_FLAGS);
    unsigned* mode  = (unsigned*)(ws + OFF_MODE);
    uint64_t* tgtb  = (uint64_t*)(ws + OFF_TGT);
    uint64_t* pposb = (uint64_t*)(ws + OFF_TGT + (size_t)BOARD_BYTES);
    uint64_t* pnegb = (uint64_t*)(ws + OFF_TGT + 2 * (size_t)BOARD_BYTES);

    hipLaunchKernelGGL(build_bits, dim3(BB * HH), dim3(512), 0, stream,
                       target, pred, tgtb, pposb, pnegb, acc);
    hipLaunchKernelGGL(flags_kernel, dim3(CC * BB), dim3(512), 0, stream,
                       tgtb, pposb, pnegb, flags, mode, acc);
    hipLaunchKernelGGL(edt_main, dim3(CC * BB * 8), dim3(512), 0, stream,
                       tgtb, pposb, pnegb, flags, mode, acc);
    hipLaunchKernelGGL(finalize_kernel, dim3(1), dim3(1), 0, stream, acc, out);
}

// Round 5
// 126.855 us; speedup vs baseline: 18.7204x; 1.0475x over previous
//
#include <hip/hip_runtime.h>
#include <stdint.h>

#define BB 16
#define CC 4
#define HH 512
#define WW 512
#define NWORDS 8          // 512 / 64
#define HW (HH * WW)

// ---------------- ws layout ----------------
// [1024]     : unsigned rowsum[C][B][H]  (bit0 anyT, bit1 anyP, bit2 anyN, bit3 allN) 128 KB
// [256K]     : u64 tgt_bits [C][B][H][NWORDS]   2 MiB
// [+2MB]     : u64 ppos_bits[C][B][H][NWORDS]  (p==1.0)
// [+4MB]     : u64 pneg_bits[C][B][H][NWORDS]  (p==0.0)
#define OFF_ROW   1024
#define OFF_TGT   262144
#define BOARD_BYTES (CC * BB * HH * NWORDS * 8)   // 2 MiB

// Fused: target bitboards + softmax p==1/p==0 bitboards + per-row summary
// nibbles + zeroing of d_out (stream order makes it visible to edt_main).
__global__ void build_bits(const int* __restrict__ tgt,
                           const float* __restrict__ pred,
                           uint64_t* __restrict__ tgtb,
                           uint64_t* __restrict__ ppos,
                           uint64_t* __restrict__ pneg,
                           unsigned* __restrict__ rowsum,
                           float* __restrict__ out) {
    __shared__ unsigned srow[CC][8];
    int row = blockIdx.x;                // 0..B*H-1
    int b = row >> 9, y = row & (HH - 1);
    int x = threadIdx.x;                 // 0..511
    if (row == 0 && x == 0) out[0] = 0.0f;

    int t = tgt[((size_t)(b * HH + y)) * WW + x];
    size_t i0 = (((size_t)b * CC) * HH + y) * (size_t)WW + x;
    float a0 = pred[i0];
    float a1 = pred[i0 + (size_t)HW];
    float a2 = pred[i0 + 2 * (size_t)HW];
    float a3 = pred[i0 + 3 * (size_t)HW];
    float m = fmaxf(fmaxf(a0, a1), fmaxf(a2, a3));
    float e0 = expf(a0 - m), e1 = expf(a1 - m), e2 = expf(a2 - m), e3 = expf(a3 - m);
    float s = (e0 + e1) + (e2 + e3);
    float p0 = e0 / s, p1 = e1 / s, p2 = e2 / s, p3 = e3 / s;

    int wv = x >> 6;
    bool l0 = (x & 63) == 0;
#define EMIT(cidx, pv)                                                        \
    {                                                                         \
        uint64_t mt = __ballot(t == (cidx));                                  \
        uint64_t mp = __ballot((pv) == 1.0f);                                 \
        uint64_t mn = __ballot((pv) == 0.0f);                                 \
        if (l0) {                                                             \
            size_t o = (((size_t)(cidx) * BB + b) * HH + y) * NWORDS + wv;    \
            tgtb[o] = mt;                                                     \
            ppos[o] = mp;                                                     \
            pneg[o] = mn;                                                     \
            srow[cidx][wv] = (mt != 0ull ? 1u : 0u) | (mp != 0ull ? 2u : 0u)  \
                           | (mn != 0ull ? 4u : 0u) | (mn == ~0ull ? 8u : 0u);\
        }                                                                     \
    }
    EMIT(0, p0)
    EMIT(1, p1)
    EMIT(2, p2)
    EMIT(3, p3)
#undef EMIT
    __syncthreads();
    if (x < CC) {
        unsigned o = 0u, a = 8u;
#pragma unroll
        for (int i = 0; i < 8; ++i) { o |= srow[x][i]; a &= srow[x][i]; }
        // bits 0..2 are ORs, bit3 is AND over the row
        rowsum[((size_t)x * BB + b) * HH + y] = (o & 7u) | a;
    }
}

__device__ __forceinline__ constexpr int lev_idx(int d2) {
    return d2==0?0: d2==1?1: d2==2?2: d2==4?3: d2==5?4: d2==8?5: d2==9?6:
           d2==10?7: d2==13?8: d2==16?9: d2==17?10: d2==18?11: d2==20?12: 13;
}

// ---------- general per-pixel helpers (cold fallback path) ----------
__device__ __forceinline__ unsigned win11(const uint64_t* row10, int idx, int p) {
    uint64_t w;
    if (p < 64) {
        w = (row10[idx] >> p) | (row10[idx + 1] << (64 - p));
    } else {
        int q = p - 64;
        uint64_t M = row10[idx + 1];
        w = q ? ((M >> q) | (row10[idx + 2] << (64 - q))) : M;
    }
    return (unsigned)w & 0x7FFu;
}

__device__ __forceinline__ void upd(int& mind2, unsigned wbits, int dy2) {
    if (wbits) {
        unsigned hi = wbits >> 5;
        unsigned lo = wbits & 31u;
        int mdx = 6;
        if (hi) mdx = __ffs(hi) - 1;
        if (lo) {
            int m2 = 5 - (31 - __clz(lo));
            mdx = min(mdx, m2);
        }
        int cand = dy2 + mdx * mdx;
        mind2 = min(mind2, cand);
    }
}

// One block per (cb, 64-row tile). Derives flags from rowsum (no separate
// flags kernel). mode fast: word-parallel level-set sum; else general
// per-pixel path. Adds normalized partials straight into out[0].
__launch_bounds__(512)
__global__ void edt_main(const uint64_t* __restrict__ tgtb,
                         const uint64_t* __restrict__ pposb,
                         const uint64_t* __restrict__ pnegb,
                         const unsigned* __restrict__ rowsum,
                         float* __restrict__ out) {
    __shared__ uint64_t shm[74 * 8];     // fast: sT[74][8]; general: sh[3][11][10]
    __shared__ float wsum[8];
    __shared__ unsigned sflag[8];
    int tile = blockIdx.x & 7;
    int cb   = blockIdx.x >> 3;
    int y0   = tile * 64;
    const float INV_N = 1.0f / 16777216.0f;   // 1/(B*H*W*C)

    // ---- derive flags for this cb from row summaries ----
    {
        unsigned rs = rowsum[(size_t)cb * HH + threadIdx.x];
        uint64_t bT = __ballot((rs & 1u) != 0u);
        uint64_t bP = __ballot((rs & 2u) != 0u);
        uint64_t bN = __ballot((rs & 4u) != 0u);
        uint64_t bAllNot = __ballot((rs & 8u) == 0u);   // rows NOT all-p==0
        if ((threadIdx.x & 63) == 0)
            sflag[threadIdx.x >> 6] = (bT ? 1u : 0u) | (bP ? 2u : 0u)
                                    | (bN ? 4u : 0u) | (bAllNot ? 8u : 0u);
        __syncthreads();
        if (threadIdx.x == 0) {
            unsigned o = 0u;
#pragma unroll
            for (int i = 0; i < 8; ++i) o |= sflag[i];
            sflag[0] = o;
        }
        __syncthreads();
    }
    unsigned F = sflag[0];
    bool present  = (F & 1u) != 0u;
    bool anyppos  = (F & 2u) != 0u;
    bool anypneg  = (F & 4u) != 0u;
    bool prednz   = (F & 8u) != 0u;   // some row not entirely p==0
    bool fast     = !anyppos && !anypneg;   // psdf == 0 uniformly
    __syncthreads();                  // sflag reuse barrier before shm writes

    if (fast) {
        if (!present) {
            // whole (c,b) contributes |0 - 3| * HW; tile 0 adds it once
            if (tile == 0 && threadIdx.x == 0)
                atomicAdd(out, 3.0f * (float)HW * INV_N);
            return;
        }
        uint64_t (*sT)[8] = (uint64_t (*)[8])shm;
        const uint64_t* board = tgtb + (size_t)cb * HH * NWORDS;
        for (int t = threadIdx.x; t < 74 * 8; t += 512) {
            int r = t >> 3, w = t & 7;
            int yy = y0 + r - 5;
            sT[r][w] = (yy >= 0 && yy < HH) ? board[(size_t)yy * NWORDS + w] : 0ull;
        }
        __syncthreads();

        int tr = threadIdx.x >> 3;    // row within tile (0..63)
        int w  = threadIdx.x & 7;     // word column (0..7)
        int y  = y0 + tr;

        uint64_t DT[14], DC[14];
#pragma unroll
        for (int k = 0; k < 14; ++k) { DT[k] = 0ull; DC[k] = 0ull; }

#pragma unroll
        for (int dy = -5; dy <= 5; ++dy) {
            int yy = y + dy;
            if (yy < 0 || yy >= HH) continue;
            const int ady  = dy < 0 ? -dy : dy;
            const int maxs = (ady == 0) ? 5 : (ady <= 3) ? 4 : (ady == 4) ? 3 : 0;
            int ly = tr + 5 + dy;
            uint64_t Cw = sT[ly][w];
            uint64_t Lw = (w > 0) ? sT[ly][w - 1] : 0ull;
            uint64_t Rw = (w < 7) ? sT[ly][w + 1] : 0ull;
            uint64_t Cc = ~Cw;
            uint64_t Lc = (w > 0) ? ~Lw : 0ull;   // outside image not in complement
            uint64_t Rc = (w < 7) ? ~Rw : 0ull;
            uint64_t UT = Cw, UC = Cc;
            DT[lev_idx(ady * ady)] |= UT;
            DC[lev_idx(ady * ady)] |= UC;
#pragma unroll
            for (int s = 1; s <= 5; ++s) {
                if (s > maxs) break;
                UT |= (Cw >> s) | (Rw << (64 - s)) | (Cw << s) | (Lw >> (64 - s));
                UC |= (Cc >> s) | (Rc << (64 - s)) | (Cc << s) | (Lc >> (64 - s));
                const int li = lev_idx(ady * ady + s * s);
                DT[li] |= UT;
                DC[li] |= UC;
            }
        }

        const float dist[14] = {0.f, 1.f, 1.41421356f, 2.f, 2.23606798f,
            2.82842712f, 3.f, 3.16227766f, 3.60555128f, 4.f, 4.12310563f,
            4.24264069f, 4.47213595f, 5.f};
        uint64_t covT = 0ull, covC = 0ull;
        float s = 0.f;
#pragma unroll
        for (int k = 0; k < 14; ++k) {
            uint64_t nT = DT[k] & ~covT;
            uint64_t nC = DC[k] & ~covC;
            s += dist[k] * (float)(__popcll(nT) + __popcll(nC));
            covT |= DT[k];
            covC |= DC[k];
        }
        s += 5.f * (float)(__popcll(~covT) + __popcll(~covC));

        for (int o = 32; o > 0; o >>= 1) s += __shfl_down(s, o, 64);
        if ((threadIdx.x & 63) == 0) wsum[threadIdx.x >> 6] = s;
        __syncthreads();
        if (threadIdx.x == 0) {
            float tot = 0.f;
#pragma unroll
            for (int i = 0; i < 8; ++i) tot += wsum[i];
            atomicAdd(out, tot * 0.2f * INV_N);   // /5 and normalize
        }
        return;
    }

    // ---------- general path (cold): per-pixel over 64 rows ----------
    uint64_t (*sh)[11][10] = (uint64_t (*)[11][10])shm;
    int x = threadIdx.x;
    int idx = x >> 6, off = x & 63, p = off + 59;
    int b = cb & (BB - 1);
    int c = cb >> 4;

    unsigned vmask = 0x7FFu;
    if (x < 5) vmask &= (0x7FFu << (5 - x)) & 0x7FFu;
    if (x > WW - 6) vmask &= 0x7FFu >> (x - (WW - 6));

    float vsum = 0.f;
    for (int yy = 0; yy < 64; ++yy) {
        int y = y0 + yy;
        __syncthreads();     // previous iteration's reads complete
        for (int t = threadIdx.x; t < 330; t += 512) {
            int m = t / 110;
            int rem = t - m * 110;
            int r = rem / 10;
            int wi = rem - r * 10;
            int rowy = y + r - 5;
            uint64_t v = 0;
            if (wi >= 1 && wi <= 8 && rowy >= 0 && rowy < HH) {
                const uint64_t* src = (m == 0) ? tgtb : (m == 1) ? pposb : pnegb;
                v = src[(((size_t)c * BB + b) * HH + rowy) * NWORDS + (wi - 1)];
            }
            sh[m][r][wi] = v;
        }
        __syncthreads();

        int tp = 26, tn = 26, qp = 26, qn = 26;
#pragma unroll
        for (int dy = -5; dy <= 5; ++dy) {
            int ady = dy < 0 ? -dy : dy;
            unsigned allowed = (ady == 0) ? 0x7FFu
                             : (ady <= 3) ? 0x3FEu
                             : (ady == 4) ? 0x1FCu
                                          : 0x020u;
            int dy2 = dy * dy;
            int r = dy + 5;
            unsigned wt  = win11(&sh[0][r][0], idx, p);
            unsigned wpp = win11(&sh[1][r][0], idx, p);
            unsigned wpn = win11(&sh[2][r][0], idx, p);
            upd(tp, wt & allowed, dy2);
            upd(tn, (~wt) & vmask & allowed, dy2);
            upd(qp, wpp & allowed, dy2);
            upd(qn, wpn & allowed, dy2);
        }

        float dtp = (tp <= 25) ? sqrtf((float)tp) : 5.0f;
        float dtn = (tn <= 25) ? sqrtf((float)tn) : 5.0f;
        float dqp = (qp <= 25) ? sqrtf((float)qp) : 5.0f;
        float dqn = (qn <= 25) ? sqrtf((float)qn) : 5.0f;

        float td = fminf(fmaxf(dtp - dtn, -5.0f), 5.0f) / 5.0f;
        float qd = fminf(fmaxf(dqp - dqn, -5.0f), 5.0f) / 5.0f;
        float tsdf = present ? td : 3.0f;
        float psdf = prednz ? qd : 3.0f;
        vsum += fabsf(psdf - tsdf);
    }

    for (int o2 = 32; o2 > 0; o2 >>= 1) vsum += __shfl_down(vsum, o2, 64);
    if (off == 0) wsum[idx] = vsum;
    __syncthreads();
    if (threadIdx.x == 0) {
        float s = 0.f;
#pragma unroll
        for (int i = 0; i < 8; ++i) s += wsum[i];
        atomicAdd(out, s * INV_N);
    }
}

extern "C" void kernel_launch(void* const* d_in, const int* in_sizes, int n_in,
                              void* d_out, int out_size, void* d_ws, size_t ws_size,
                              hipStream_t stream) {
    const float* pred  = (const float*)d_in[0];
    const int* target  = (const int*)d_in[1];
    float* out = (float*)d_out;

    char* ws = (char*)d_ws;
    unsigned* rowsum = (unsigned*)(ws + OFF_ROW);
    uint64_t* tgtb   = (uint64_t*)(ws + OFF_TGT);
    uint64_t* pposb  = (uint64_t*)(ws + OFF_TGT + (size_t)BOARD_BYTES);
    uint64_t* pnegb  = (uint64_t*)(ws + OFF_TGT + 2 * (size_t)BOARD_BYTES);

    hipLaunchKernelGGL(build_bits, dim3(BB * HH), dim3(512), 0, stream,
                       target, pred, tgtb, pposb, pnegb, rowsum, out);
    hipLaunchKernelGGL(edt_main, dim3(CC * BB * 8), dim3(512), 0, stream,
                       tgtb, pposb, pnegb, rowsum, out);
}

// Round 7
// 126.701 us; speedup vs baseline: 18.7432x; 1.0012x over previous
//
#include <hip/hip_runtime.h>
#include <stdint.h>

#define BB 16
#define CC 4
#define HH 512
#define WW 512
#define NWORDS 8          // 512 / 64
#define HW (HH * WW)

// ---------------- ws layout ----------------
// [1024]     : unsigned rowsum[C][B][H]  (bit0 anyT, bit1 anyP, bit2 anyN, bit3 allN) 128 KB
// [256K]     : u64 tgt_bits [C][B][H][NWORDS]   2 MiB
// [+2MB]     : u64 ppos_bits[C][B][H][NWORDS]  (p==1.0)
// [+4MB]     : u64 pneg_bits[C][B][H][NWORDS]  (p==0.0)
#define OFF_ROW   1024
#define OFF_TGT   262144
#define BOARD_BYTES (CC * BB * HH * NWORDS * 8)   // 2 MiB

// Fused: target bitboards + softmax p==1/p==0 bitboards + per-row summary
// nibbles + zeroing of d_out (stream order makes it visible to edt_main).
__global__ void build_bits(const int* __restrict__ tgt,
                           const float* __restrict__ pred,
                           uint64_t* __restrict__ tgtb,
                           uint64_t* __restrict__ ppos,
                           uint64_t* __restrict__ pneg,
                           unsigned* __restrict__ rowsum,
                           float* __restrict__ out) {
    __shared__ unsigned srow[CC][8];
    int row = blockIdx.x;                // 0..B*H-1
    int b = row >> 9, y = row & (HH - 1);
    int x = threadIdx.x;                 // 0..511
    if (row == 0 && x == 0) out[0] = 0.0f;

    int t = tgt[((size_t)(b * HH + y)) * WW + x];
    size_t i0 = (((size_t)b * CC) * HH + y) * (size_t)WW + x;
    float a0 = pred[i0];
    float a1 = pred[i0 + (size_t)HW];
    float a2 = pred[i0 + 2 * (size_t)HW];
    float a3 = pred[i0 + 3 * (size_t)HW];
    float m = fmaxf(fmaxf(a0, a1), fmaxf(a2, a3));
    float e0 = expf(a0 - m), e1 = expf(a1 - m), e2 = expf(a2 - m), e3 = expf(a3 - m);
    float s = (e0 + e1) + (e2 + e3);
    float p0 = e0 / s, p1 = e1 / s, p2 = e2 / s, p3 = e3 / s;

    int wv = x >> 6;
    bool l0 = (x & 63) == 0;
#define EMIT(cidx, pv)                                                        \
    {                                                                         \
        uint64_t mt = __ballot(t == (cidx));                                  \
        uint64_t mp = __ballot((pv) == 1.0f);                                 \
        uint64_t mn = __ballot((pv) == 0.0f);                                 \
        if (l0) {                                                             \
            size_t o = (((size_t)(cidx) * BB + b) * HH + y) * NWORDS + wv;    \
            tgtb[o] = mt;                                                     \
            ppos[o] = mp;                                                     \
            pneg[o] = mn;                                                     \
            srow[cidx][wv] = (mt != 0ull ? 1u : 0u) | (mp != 0ull ? 2u : 0u)  \
                           | (mn != 0ull ? 4u : 0u) | (mn == ~0ull ? 8u : 0u);\
        }                                                                     \
    }
    EMIT(0, p0)
    EMIT(1, p1)
    EMIT(2, p2)
    EMIT(3, p3)
#undef EMIT
    __syncthreads();
    if (x < CC) {
        unsigned o = 0u, a = 8u;
#pragma unroll
        for (int i = 0; i < 8; ++i) { o |= srow[x][i]; a &= srow[x][i]; }
        // bits 0..2 are ORs, bit3 is AND over the row
        rowsum[((size_t)x * BB + b) * HH + y] = (o & 7u) | a;
    }
}

__device__ __forceinline__ constexpr int lev_idx(int d2) {
    return d2==0?0: d2==1?1: d2==2?2: d2==4?3: d2==5?4: d2==8?5: d2==9?6:
           d2==10?7: d2==13?8: d2==16?9: d2==17?10: d2==18?11: d2==20?12: 13;
}

// ---------- general per-pixel helpers (cold fallback path) ----------
__device__ __forceinline__ unsigned win11(const uint64_t* row10, int idx, int p) {
    uint64_t w;
    if (p < 64) {
        w = (row10[idx] >> p) | (row10[idx + 1] << (64 - p));
    } else {
        int q = p - 64;
        uint64_t M = row10[idx + 1];
        w = q ? ((M >> q) | (row10[idx + 2] << (64 - q))) : M;
    }
    return (unsigned)w & 0x7FFu;
}

__device__ __forceinline__ void upd(int& mind2, unsigned wbits, int dy2) {
    if (wbits) {
        unsigned hi = wbits >> 5;
        unsigned lo = wbits & 31u;
        int mdx = 6;
        if (hi) mdx = __ffs(hi) - 1;
        if (lo) {
            int m2 = 5 - (31 - __clz(lo));
            mdx = min(mdx, m2);
        }
        int cand = dy2 + mdx * mdx;
        mind2 = min(mind2, cand);
    }
}

// One block per (cb, 64-row tile). Derives flags from rowsum (no separate
// flags kernel). mode fast: word-parallel level-set sum; else general
// per-pixel path. Adds normalized partials straight into out[0].
__launch_bounds__(512)
__global__ void edt_main(const uint64_t* __restrict__ tgtb,
                         const uint64_t* __restrict__ pposb,
                         const uint64_t* __restrict__ pnegb,
                         const unsigned* __restrict__ rowsum,
                         float* __restrict__ out) {
    __shared__ uint64_t shm[74 * 8];     // fast: sT[74][8]; general: sh[3][11][10]
    __shared__ float wsum[8];
    __shared__ unsigned sflag[8];
    int tile = blockIdx.x & 7;
    int cb   = blockIdx.x >> 3;
    int y0   = tile * 64;
    const float INV_N = 1.0f / 16777216.0f;   // 1/(B*H*W*C)

    // ---- derive flags for this cb from row summaries ----
    {
        unsigned rs = rowsum[(size_t)cb * HH + threadIdx.x];
        uint64_t bT = __ballot((rs & 1u) != 0u);
        uint64_t bP = __ballot((rs & 2u) != 0u);
        uint64_t bN = __ballot((rs & 4u) != 0u);
        uint64_t bAllNot = __ballot((rs & 8u) == 0u);   // rows NOT all-p==0
        if ((threadIdx.x & 63) == 0)
            sflag[threadIdx.x >> 6] = (bT ? 1u : 0u) | (bP ? 2u : 0u)
                                    | (bN ? 4u : 0u) | (bAllNot ? 8u : 0u);
        __syncthreads();
        if (threadIdx.x == 0) {
            unsigned o = 0u;
#pragma unroll
            for (int i = 0; i < 8; ++i) o |= sflag[i];
            sflag[0] = o;
        }
        __syncthreads();
    }
    unsigned F = sflag[0];
    bool present  = (F & 1u) != 0u;
    bool anyppos  = (F & 2u) != 0u;
    bool anypneg  = (F & 4u) != 0u;
    bool prednz   = (F & 8u) != 0u;   // some row not entirely p==0
    bool fast     = !anyppos && !anypneg;   // psdf == 0 uniformly
    __syncthreads();                  // sflag settle before shm writes

    if (fast) {
        if (!present) {
            // whole (c,b) contributes |0 - 3| * HW; tile 0 adds it once
            if (tile == 0 && threadIdx.x == 0)
                atomicAdd(out, 3.0f * (float)HW * INV_N);
            return;
        }
        uint64_t (*sT)[8] = (uint64_t (*)[8])shm;
        const uint64_t* board = tgtb + (size_t)cb * HH * NWORDS;
        for (int t = threadIdx.x; t < 74 * 8; t += 512) {
            int r = t >> 3, w = t & 7;
            int yy = y0 + r - 5;
            sT[r][w] = (yy >= 0 && yy < HH) ? board[(size_t)yy * NWORDS + w] : 0ull;
        }
        __syncthreads();

        int tr = threadIdx.x >> 3;    // row within tile (0..63)
        int w  = threadIdx.x & 7;     // word column (0..7)
        int y  = y0 + tr;

        uint64_t DT[14], DC[14];
#pragma unroll
        for (int k = 0; k < 14; ++k) { DT[k] = 0ull; DC[k] = 0ull; }

#pragma unroll
        for (int dy = -5; dy <= 5; ++dy) {
            int yy = y + dy;
            if (yy < 0 || yy >= HH) continue;
            const int ady  = dy < 0 ? -dy : dy;
            const int maxs = (ady == 0) ? 5 : (ady <= 3) ? 4 : (ady == 4) ? 3 : 0;
            int ly = tr + 5 + dy;
            uint64_t Cw = sT[ly][w];
            uint64_t Lw = (w > 0) ? sT[ly][w - 1] : 0ull;
            uint64_t Rw = (w < 7) ? sT[ly][w + 1] : 0ull;
            uint64_t Cc = ~Cw;
            uint64_t Lc = (w > 0) ? ~Lw : 0ull;   // outside image not in complement
            uint64_t Rc = (w < 7) ? ~Rw : 0ull;
            uint64_t UT = Cw, UC = Cc;
            DT[lev_idx(ady * ady)] |= UT;
            DC[lev_idx(ady * ady)] |= UC;
#pragma unroll
            for (int s = 1; s <= 5; ++s) {
                if (s > maxs) break;
                UT |= (Cw >> s) | (Rw << (64 - s)) | (Cw << s) | (Lw >> (64 - s));
                UC |= (Cc >> s) | (Rc << (64 - s)) | (Cc << s) | (Lc >> (64 - s));
                const int li = lev_idx(ady * ady + s * s);
                DT[li] |= UT;
                DC[li] |= UC;
            }
        }

        const float dist[14] = {0.f, 1.f, 1.41421356f, 2.f, 2.23606798f,
            2.82842712f, 3.f, 3.16227766f, 3.60555128f, 4.f, 4.12310563f,
            4.24264069f, 4.47213595f, 5.f};
        uint64_t covT = 0ull, covC = 0ull;
        float s = 0.f;
#pragma unroll
        for (int k = 0; k < 14; ++k) {
            uint64_t nT = DT[k] & ~covT;
            uint64_t nC = DC[k] & ~covC;
            s += dist[k] * (float)(__popcll(nT) + __popcll(nC));
            covT |= DT[k];
            covC |= DC[k];
        }
        s += 5.f * (float)(__popcll(~covT) + __popcll(~covC));

        for (int o = 32; o > 0; o >>= 1) s += __shfl_down(s, o, 64);
        if ((threadIdx.x & 63) == 0) wsum[threadIdx.x >> 6] = s;
        __syncthreads();
        if (threadIdx.x == 0) {
            float tot = 0.f;
#pragma unroll
            for (int i = 0; i < 8; ++i) tot += wsum[i];
            atomicAdd(out, tot * 0.2f * INV_N);   // /5 and normalize
        }
        return;
    }

    // ---------- general path (cold): per-pixel over 64 rows ----------
    uint64_t (*sh)[11][10] = (uint64_t (*)[11][10])shm;
    int x = threadIdx.x;
    int idx = x >> 6, off = x & 63, p = off + 59;
    int b = cb & (BB - 1);
    int c = cb >> 4;

    unsigned vmask = 0x7FFu;
    if (x < 5) vmask &= (0x7FFu << (5 - x)) & 0x7FFu;
    if (x > WW - 6) vmask &= 0x7FFu >> (x - (WW - 6));

    float vsum = 0.f;
    for (int yy = 0; yy < 64; ++yy) {
        int y = y0 + yy;
        __syncthreads();     // previous iteration's reads complete
        for (int t = threadIdx.x; t < 330; t += 512) {
            int m = t / 110;
            int rem = t - m * 110;
            int r = rem / 10;
            int wi = rem - r * 10;
            int rowy = y + r - 5;
            uint64_t v = 0;
            if (wi >= 1 && wi <= 8 && rowy >= 0 && rowy < HH) {
                const uint64_t* src = (m == 0) ? tgtb : (m == 1) ? pposb : pnegb;
                v = src[(((size_t)c * BB + b) * HH + rowy) * NWORDS + (wi - 1)];
            }
            sh[m][r][wi] = v;
        }
        __syncthreads();

        int tp = 26, tn = 26, qp = 26, qn = 26;
#pragma unroll
        for (int dy = -5; dy <= 5; ++dy) {
            int ady = dy < 0 ? -dy : dy;
            unsigned allowed = (ady == 0) ? 0x7FFu
                             : (ady <= 3) ? 0x3FEu
                             : (ady == 4) ? 0x1FCu
                                          : 0x020u;
            int dy2 = dy * dy;
            int r = dy + 5;
            unsigned wt  = win11(&sh[0][r][0], idx, p);
            unsigned wpp = win11(&sh[1][r][0], idx, p);
            unsigned wpn = win11(&sh[2][r][0], idx, p);
            upd(tp, wt & allowed, dy2);
            upd(tn, (~wt) & vmask & allowed, dy2);
            upd(qp, wpp & allowed, dy2);
            upd(qn, wpn & allowed, dy2);
        }

        float dtp = (tp <= 25) ? sqrtf((float)tp) : 5.0f;
        float dtn = (tn <= 25) ? sqrtf((float)tn) : 5.0f;
        float dqp = (qp <= 25) ? sqrtf((float)qp) : 5.0f;
        float dqn = (qn <= 25) ? sqrtf((float)qn) : 5.0f;

        float td = fminf(fmaxf(dtp - dtn, -5.0f), 5.0f) / 5.0f;
        float qd = fminf(fmaxf(dqp - dqn, -5.0f), 5.0f) / 5.0f;
        float tsdf = present ? td : 3.0f;
        float psdf = prednz ? qd : 3.0f;
        vsum += fabsf(psdf - tsdf);
    }

    for (int o2 = 32; o2 > 0; o2 >>= 1) vsum += __shfl_down(vsum, o2, 64);
    if (off == 0) wsum[idx] = vsum;
    __syncthreads();
    if (threadIdx.x == 0) {
        float s = 0.f;
#pragma unroll
        for (int i = 0; i < 8; ++i) s += wsum[i];
        atomicAdd(out, s * INV_N);
    }
}

extern "C" void kernel_launch(void* const* d_in, const int* in_sizes, int n_in,
                              void* d_out, int out_size, void* d_ws, size_t ws_size,
                              hipStream_t stream) {
    const float* pred  = (const float*)d_in[0];
    const int* target  = (const int*)d_in[1];
    float* out = (float*)d_out;

    char* ws = (char*)d_ws;
    unsigned* rowsum = (unsigned*)(ws + OFF_ROW);
    uint64_t* tgtb   = (uint64_t*)(ws + OFF_TGT);
    uint64_t* pposb  = (uint64_t*)(ws + OFF_TGT + (size_t)BOARD_BYTES);
    uint64_t* pnegb  = (uint64_t*)(ws + OFF_TGT + 2 * (size_t)BOARD_BYTES);

    hipLaunchKernelGGL(build_bits, dim3(BB * HH), dim3(512), 0, stream,
                       target, pred, tgtb, pposb, pnegb, rowsum, out);
    hipLaunchKernelGGL(edt_main, dim3(CC * BB * 8), dim3(512), 0, stream,
                       tgtb, pposb, pnegb, rowsum, out);
}